// Round 1
// baseline (323.031 us; speedup 1.0000x reference)
//
#include <hip/hip_runtime.h>

// B=256, N=65536, fp32 complex multiply.
// Output row layout (verified by the passing baseline): each 2N-float row is
// [real[0..N) , imag[0..N)]; the reference's reshape(-1,2) just pairs
// consecutive floats of that flat sequence.
//
// Design (vs. the 110 us/dispatch baseline):
//  * Every memory instruction is lane-contiguous:
//      - one float4 load per input per slot (16 B/lane, 1 KiB/instr)
//      - one float2 store to the real region + one to the imag region
//        (8 B/lane, 512 B/instr) -- no more 32B-strided half-line loads.
//  * Grid-stride style tiling per Guideline 11: 2048 blocks (8/CU) x 256
//    threads, 16 slots/thread, unrolled x4 so 8 independent float4 loads
//    are in flight per thread between s_waitcnts.
//  * Nontemporal stores: the 134 MB output stream is never re-read; keep it
//    from evicting the 268 MB input set out of the 256 MB L3.

#define N_COMPLEX   65536
#define ROW_F4_IN   (N_COMPLEX / 2)    // 32768 float4 per row per input
#define IMAG_OFF_F2 (N_COMPLEX / 2)    // 32768 float2 offset to imag region
#define BLOCK       256
#define GRID        2048
#define STRIDE      (BLOCK * GRID)     // 524288 float4 per sweep
#define TOTAL_F4    (256 * (N_COMPLEX / 2))   // 8,388,608 float4 per input
#define ITERS       (TOTAL_F4 / STRIDE)       // 16 slots per thread (exact)
#define UNROLL      4

typedef float f32x2 __attribute__((ext_vector_type(2)));
typedef float f32x4 __attribute__((ext_vector_type(4)));

__global__ __launch_bounds__(BLOCK) void cmul_kernel(
        const f32x4* __restrict__ a,
        const f32x4* __restrict__ b,
        f32x2* __restrict__ out) {
    unsigned idx = blockIdx.x * BLOCK + threadIdx.x;
    #pragma unroll 1
    for (int o = 0; o < ITERS / UNROLL; ++o) {
        f32x4 va[UNROLL], vb[UNROLL];
        unsigned id[UNROLL];
        #pragma unroll
        for (int i = 0; i < UNROLL; ++i) {
            id[i] = idx + (unsigned)i * STRIDE;
            va[i] = a[id[i]];
            vb[i] = b[id[i]];
        }
        #pragma unroll
        for (int i = 0; i < UNROLL; ++i) {
            // float4 = 2 complex: (re0, im0, re1, im1)
            f32x2 re, im;
            re.x = va[i].x * vb[i].x - va[i].y * vb[i].y;
            im.x = va[i].y * vb[i].x + va[i].x * vb[i].y;
            re.y = va[i].z * vb[i].z - va[i].w * vb[i].w;
            im.y = va[i].w * vb[i].z + va[i].z * vb[i].w;
            // row = id >> 15; out_f2 = row*65536 + (id & 32767)
            const unsigned r2 = ((id[i] & ~(unsigned)(ROW_F4_IN - 1)) << 1)
                              | (id[i] & (unsigned)(ROW_F4_IN - 1));
            __builtin_nontemporal_store(re, &out[r2]);
            __builtin_nontemporal_store(im, &out[r2 + IMAG_OFF_F2]);
        }
        idx += UNROLL * STRIDE;
    }
}

extern "C" void kernel_launch(void* const* d_in, const int* in_sizes, int n_in,
                              void* d_out, int out_size, void* d_ws, size_t ws_size,
                              hipStream_t stream) {
    (void)in_sizes; (void)n_in; (void)d_ws; (void)ws_size; (void)out_size;
    cmul_kernel<<<GRID, BLOCK, 0, stream>>>((const f32x4*)d_in[0],
                                            (const f32x4*)d_in[1],
                                            (f32x2*)d_out);
}

// Round 3
// 313.889 us; speedup vs baseline: 1.0291x; 1.0291x over previous
//
#include <hip/hip_runtime.h>

// B=256, N=65536, fp32 complex multiply.
// out row (2N floats) = [real[0..N), imag[0..N)); reshape(-1,2) pairs floats.
//
// Round-3 = Round-2 resubmit (bench infra failed; no counters returned).
// Design: one-shot structure (v0-proven), ONE change vs v0: each thread owns
// TWO independent far-apart pair-groups, all 8 input loads issued up-front.
//   - 2x in-flight read bytes per wave (8 KB vs 4 KB)
//   - half the wave launch/drain overhead
//   - shot1's loads stay in flight (vmcnt(4)) while shot0 computes/stores.

#define N_COMPLEX   65536
#define PAIRS_ROW   (N_COMPLEX / 4)      // 16384 4-complex groups per row
#define ROW_F4      (2 * N_COMPLEX / 4)  // 32768 float4 per output row
#define IMAG_OFF_F4 (N_COMPLEX / 4)      // 16384
#define TOTAL_PAIRS (256 * PAIRS_ROW)    // 4,194,304
#define HALF_PAIRS  (TOTAL_PAIRS / 2)    // 2,097,152
#define BLOCK       256

__device__ __forceinline__ void cmul4(const float4& x0, const float4& x1,
                                      const float4& y0, const float4& y1,
                                      float4& re, float4& im) {
    re.x = x0.x * y0.x - x0.y * y0.y;
    im.x = x0.y * y0.x + x0.x * y0.y;
    re.y = x0.z * y0.z - x0.w * y0.w;
    im.y = x0.w * y0.z + x0.z * y0.w;
    re.z = x1.x * y1.x - x1.y * y1.y;
    im.z = x1.y * y1.x + x1.x * y1.y;
    re.w = x1.z * y1.z - x1.w * y1.w;
    im.w = x1.w * y1.z + x1.z * y1.w;
}

__global__ __launch_bounds__(BLOCK) void cmul_kernel(
        const float4* __restrict__ a,
        const float4* __restrict__ b,
        float4* __restrict__ out) {
    const unsigned t  = blockIdx.x * BLOCK + threadIdx.x;
    const unsigned p0 = t;                 // pair-group 0
    const unsigned p1 = t + HALF_PAIRS;    // pair-group 1 (far half)

    const size_t i0 = (size_t)p0 * 2;
    const size_t i1 = (size_t)p1 * 2;

    // Issue all 8 loads up-front (independent; shot0 compute waits vmcnt(4),
    // shot1's loads stay in flight).
    const float4 a00 = a[i0], a01 = a[i0 + 1];
    const float4 b00 = b[i0], b01 = b[i0 + 1];
    const float4 a10 = a[i1], a11 = a[i1 + 1];
    const float4 b10 = b[i1], b11 = b[i1 + 1];

    // ---- shot 0 ----
    {
        float4 re, im;
        cmul4(a00, a01, b00, b01, re, im);
        const unsigned row = p0 >> 14;            // p0 / PAIRS_ROW
        const unsigned n4  = p0 & (PAIRS_ROW - 1);
        const size_t base = (size_t)row * ROW_F4 + n4;
        out[base]               = re;
        out[base + IMAG_OFF_F4] = im;
    }
    // ---- shot 1 ----
    {
        float4 re, im;
        cmul4(a10, a11, b10, b11, re, im);
        const unsigned row = p1 >> 14;
        const unsigned n4  = p1 & (PAIRS_ROW - 1);
        const size_t base = (size_t)row * ROW_F4 + n4;
        out[base]               = re;
        out[base + IMAG_OFF_F4] = im;
    }
}

extern "C" void kernel_launch(void* const* d_in, const int* in_sizes, int n_in,
                              void* d_out, int out_size, void* d_ws, size_t ws_size,
                              hipStream_t stream) {
    (void)in_sizes; (void)n_in; (void)d_ws; (void)ws_size; (void)out_size;
    const int grid = HALF_PAIRS / BLOCK;   // 8192 blocks, one-shot
    cmul_kernel<<<grid, BLOCK, 0, stream>>>((const float4*)d_in[0],
                                            (const float4*)d_in[1],
                                            (float4*)d_out);
}

// Round 4
// 302.795 us; speedup vs baseline: 1.0668x; 1.0366x over previous
//
#include <hip/hip_runtime.h>

// B=256, N=65536, fp32 complex multiply.
// out row (2N floats) = [real[0..N), imag[0..N)); reshape(-1,2) pairs floats.
//
// Round-4: isolate READ CONTIGUITY in the proven one-shot structure.
//   v0/R3 loads were lane-strided (a[2t], a[2t+1]: 32 B apart per lane per
//   instruction) -> each load instr touches 16 cache lines, half-consumed,
//   re-requested by the neighbor instr => 2x line requests on the read side.
//   Here each thread owns exactly ONE float4 (2 complex): lane i loads
//   a[base+i] / b[base+i] -> 1 KiB fully-consumed contiguous per instruction.
//   Stores: two float2 (512 B/instr, full lines per wave).
// Depth (R3) and persistence (R1) are individually falsified; this is the
// last un-isolated structural variable.

#define N_COMPLEX  65536
#define ROW_F4_IN  (N_COMPLEX / 2)     // 32768 float4 per input row
#define ROW_F2_OUT N_COMPLEX           // 65536 float2 per output row
#define IMAG_OFF_F2 (N_COMPLEX / 2)    // 32768 float2 to imag region
#define BLOCK      256
#define TOTAL_F4   (256 * ROW_F4_IN)   // 8,388,608 float4 per input

typedef float f32x2 __attribute__((ext_vector_type(2)));

__global__ __launch_bounds__(BLOCK) void cmul_kernel(
        const float4* __restrict__ a,
        const float4* __restrict__ b,
        f32x2* __restrict__ out) {
    const unsigned t = blockIdx.x * BLOCK + threadIdx.x;   // float4 index

    const float4 va = a[t];
    const float4 vb = b[t];

    // float4 = 2 complex: (re0, im0, re1, im1)
    f32x2 re, im;
    re.x = va.x * vb.x - va.y * vb.y;
    im.x = va.y * vb.x + va.x * vb.y;
    re.y = va.z * vb.z - va.w * vb.w;
    im.y = va.w * vb.z + va.z * vb.w;

    const unsigned row = t >> 15;                 // t / ROW_F4_IN
    const unsigned c2  = t & (ROW_F4_IN - 1);     // float2 index in real region
    const unsigned base = row * ROW_F2_OUT + c2;
    out[base]               = re;
    out[base + IMAG_OFF_F2] = im;
}

extern "C" void kernel_launch(void* const* d_in, const int* in_sizes, int n_in,
                              void* d_out, int out_size, void* d_ws, size_t ws_size,
                              hipStream_t stream) {
    (void)in_sizes; (void)n_in; (void)d_ws; (void)ws_size; (void)out_size;
    const int grid = TOTAL_F4 / BLOCK;   // 32768 one-shot blocks
    cmul_kernel<<<grid, BLOCK, 0, stream>>>((const float4*)d_in[0],
                                            (const float4*)d_in[1],
                                            (f32x2*)d_out);
}

// Round 5
// 300.604 us; speedup vs baseline: 1.0746x; 1.0073x over previous
//
#include <hip/hip_runtime.h>

// B=256, N=65536, fp32 complex multiply.
// out row (2N floats) = [real[0..N), imag[0..N)); reshape(-1,2) pairs floats.
//
// Round-5: cut memory-instruction count 4 -> 3 per 64-float4 chunk.
// R4 (104 us) used 2 loads + 2 float2 stores. Here a lane-pair shuffle
// (shfl_xor 1) repacks so even lanes hold a full re-float4 and odd lanes a
// full im-float4 -> ONE 16 B/lane store instead of two 8 B/lane stores.
// All memory instructions are fully-coalesced 16 B/lane. VALU cost of the
// shuffle is free (VALUBusy 5.5%).
//
// Mapping check (wave covers 64 consecutive float4 = 128 complex):
//   lane 2j   : re-quad  re[4j..4j+4) = own (re0,re1) + lane2j+1's (re0,re1)
//   lane 2j+1 : im-quad  im[4j..4j+4) = lane2j's (im0,im1) + own (im0,im1)
//   out float4 idx = row*32768 + (r4>>1) + (lane&1)*16384   (r4 = in-f4 % row)

#define N_COMPLEX   65536
#define ROW_F4_IN   (N_COMPLEX / 2)    // 32768 float4 per input row
#define ROW_F4_OUT  (N_COMPLEX / 2)    // 32768 float4 per output row
#define IMAG_OFF_F4 (N_COMPLEX / 4)    // 16384 float4 to imag region
#define BLOCK       256
#define TOTAL_F4    (256 * ROW_F4_IN)  // 8,388,608 float4 per input

__global__ __launch_bounds__(BLOCK) void cmul_kernel(
        const float4* __restrict__ a,
        const float4* __restrict__ b,
        float4* __restrict__ out) {
    const unsigned t    = blockIdx.x * BLOCK + threadIdx.x;  // float4 index
    const unsigned lane = threadIdx.x & 63;
    const unsigned odd  = lane & 1;

    const float4 va = a[t];
    const float4 vb = b[t];

    // float4 = 2 complex: (re0, im0, re1, im1)
    const float re0 = va.x * vb.x - va.y * vb.y;
    const float im0 = va.y * vb.x + va.x * vb.y;
    const float re1 = va.z * vb.z - va.w * vb.w;
    const float im1 = va.w * vb.z + va.z * vb.w;

    // Even lane sends its im pair, odd lane sends its re pair.
    const float s0 = odd ? re0 : im0;
    const float s1 = odd ? re1 : im1;
    const float r0 = __shfl_xor(s0, 1, 64);
    const float r1 = __shfl_xor(s1, 1, 64);

    float4 o;   // even: (re0, re1, r0, r1)   odd: (r0, r1, im0, im1)
    o.x = odd ? r0  : re0;
    o.y = odd ? r1  : re1;
    o.z = odd ? im0 : r0;
    o.w = odd ? im1 : r1;

    const unsigned row = t >> 15;                // t / ROW_F4_IN
    const unsigned r4  = t & (ROW_F4_IN - 1);
    const unsigned o4  = row * ROW_F4_OUT + (r4 >> 1) + (odd ? IMAG_OFF_F4 : 0u);
    out[o4] = o;
}

extern "C" void kernel_launch(void* const* d_in, const int* in_sizes, int n_in,
                              void* d_out, int out_size, void* d_ws, size_t ws_size,
                              hipStream_t stream) {
    (void)in_sizes; (void)n_in; (void)d_ws; (void)ws_size; (void)out_size;
    const int grid = TOTAL_F4 / BLOCK;   // 32768 one-shot blocks
    cmul_kernel<<<grid, BLOCK, 0, stream>>>((const float4*)d_in[0],
                                            (const float4*)d_in[1],
                                            (float4*)d_out);
}